// Round 7
// baseline (381.011 us; speedup 1.0000x reference)
//
#include <hip/hip_runtime.h>
#include <hip/hip_fp16.h>

// Problem constants (fixed-size problem)
#define NNODES 100000
#define NEDGES 1600000
#define IN_C   128
#define HID_C  128
#define OUT_C  64

#define SCAN_BLOCKS ((NNODES + 255) / 256)  // 391
#define XCD_COUNT   8
#define XCD_NODES   ((NNODES + XCD_COUNT - 1) / XCD_COUNT)  // 12500

#define PART_U      4
#define PART_EDGES  (256 * PART_U)  // 1024 edges per block
#define PART_BLOCKS ((NEDGES + PART_EDGES - 1) / PART_EDGES)  // 1563
#define BUCKET_CAP  400000          // >> expected 200k/bucket (uniform dst)
#define FILL_BPB    128             // fill blocks per bucket

typedef __attribute__((ext_vector_type(8))) _Float16 half8;
typedef __attribute__((ext_vector_type(4))) _Float16 half4;
typedef __attribute__((ext_vector_type(4))) float floatx4;

// ---------------------------------------------------------------------------
// Index width handling (int64 per reference vs int32 from JAX default)
// ---------------------------------------------------------------------------
__device__ __forceinline__ long long load_idx(const void* p, long long i, int is64) {
  return is64 ? ((const long long*)p)[i] : (long long)((const int*)p)[i];
}

__global__ void detect_idx_kernel(const void* eidx, int* flag) {
  const unsigned* w = (const unsigned*)eidx;
  int lane = threadIdx.x & 63;
  unsigned v = w[2 * lane + 1];
  unsigned long long bad = __ballot(v != 0u);
  if (lane == 0) *flag = (bad == 0ull) ? 1 : 0;
}

// ===========================================================================
// CSR build
// ===========================================================================

__global__ void zero_int_kernel(int* p, int n) {
  int i = blockIdx.x * 256 + threadIdx.x;
  if (i < n) p[i] = 0;
}

__global__ void init_bcur_kernel(int* bcur) {
  int t = threadIdx.x;
  if (t < XCD_COUNT) bcur[t] = t * BUCKET_CAP;
}

// Single-pass radix partition of edges by dst slice (8 buckets) + per-node
// in-degree histogram. Each block: LDS-count its 1024 edges per bucket,
// reserve ranges with 8 global atomics, then write (src,dst) int2 pairs.
__global__ __launch_bounds__(256) void partition_kernel(const void* eidx,
                                                        const int* __restrict__ flag,
                                                        int* __restrict__ cnt,
                                                        int* __restrict__ bcur,
                                                        int2* __restrict__ ebuf) {
  __shared__ int lcount[XCD_COUNT];
  __shared__ int lcur[XCD_COUNT];
  const int t = threadIdx.x;
  if (t < XCD_COUNT) lcount[t] = 0;
  __syncthreads();

  const int is64 = *flag;
  const int e0 = blockIdx.x * PART_EDGES + t;
  int s[PART_U], d[PART_U], b[PART_U];
  bool valid[PART_U];
#pragma unroll
  for (int u = 0; u < PART_U; ++u) {
    int e = e0 + u * 256;
    valid[u] = (e < NEDGES);
    if (valid[u]) {
      s[u] = (int)load_idx(eidx, e, is64);
      d[u] = (int)load_idx(eidx, (long long)NEDGES + e, is64);
      b[u] = d[u] / XCD_NODES;
      atomicAdd(&cnt[d[u]], 1);
      atomicAdd(&lcount[b[u]], 1);
    }
  }
  __syncthreads();
  if (t < XCD_COUNT) lcur[t] = atomicAdd(&bcur[t], lcount[t]);
  __syncthreads();
#pragma unroll
  for (int u = 0; u < PART_U; ++u) {
    if (valid[u]) {
      int pos = atomicAdd(&lcur[b[u]], 1);
      ebuf[pos] = make_int2(s[u], d[u]);
    }
  }
}

// --- Parallel 3-phase exclusive scan of cnt[NNODES] ---
__global__ __launch_bounds__(256) void scan_partial_kernel(const int* __restrict__ cnt,
                                                           int* __restrict__ partial) {
  __shared__ int red[256];
  int t = threadIdx.x;
  int i = blockIdx.x * 256 + t;
  int v = (i < NNODES) ? cnt[i] : 0;
  red[t] = v;
  __syncthreads();
#pragma unroll
  for (int off = 128; off > 0; off >>= 1) {
    if (t < off) red[t] += red[t + off];
    __syncthreads();
  }
  if (t == 0) partial[blockIdx.x] = red[0];
}

__global__ __launch_bounds__(512) void scan_base_kernel(int* __restrict__ partial) {
  __shared__ int s[512];
  int t = threadIdx.x;
  int v = (t < SCAN_BLOCKS) ? partial[t] : 0;
  s[t] = v;
  __syncthreads();
  for (int off = 1; off < 512; off <<= 1) {
    int other = (t >= off) ? s[t - off] : 0;
    __syncthreads();
    s[t] += other;
    __syncthreads();
  }
  if (t < SCAN_BLOCKS) partial[t] = s[t] - v;  // exclusive base
}

__global__ __launch_bounds__(256) void scan_final_kernel(const int* __restrict__ cnt_in,
                                                         const int* __restrict__ partial,
                                                         int* __restrict__ row_start,
                                                         int* __restrict__ cursor,
                                                         float* __restrict__ dinv) {
  __shared__ int s[256];
  int t = threadIdx.x;
  int i = blockIdx.x * 256 + t;
  int c = (i < NNODES) ? cnt_in[i] : 0;
  s[t] = c;
  __syncthreads();
  int acc = c;
  for (int off = 1; off < 256; off <<= 1) {
    int other = (t >= off) ? s[t - off] : 0;
    __syncthreads();
    acc += other;
    s[t] = acc;
    __syncthreads();
  }
  if (i < NNODES) {
    int rs = partial[blockIdx.x] + acc - c;  // exclusive
    row_start[i] = rs;
    cursor[i] = rs;
    dinv[i] = rsqrtf((float)(c + 1));
    if (i == NNODES - 1) row_start[NNODES] = NEDGES;
  }
}

// All-hit per-bucket CSR fill: bucket b's blocks (blockIdx&7 == b -> XCD b
// round-robin heuristic) read only their own contiguous edge segment; cursor
// atomics + csr stores land in that XCD's L2-resident slice.
__global__ __launch_bounds__(256) void fill_bucket_kernel(const int2* __restrict__ ebuf,
                                                          const int* __restrict__ bcur,
                                                          int* __restrict__ cursor,
                                                          int* __restrict__ csr_src) {
  const int b = blockIdx.x & (XCD_COUNT - 1);
  const int j = blockIdx.x >> 3;
  const int beg = b * BUCKET_CAP;
  const int end = bcur[b];
  for (int e = beg + j * 256 + threadIdx.x; e < end; e += FILL_BPB * 256) {
    int2 p = ebuf[e];
    int pos = atomicAdd(&cursor[p.y], 1);
    csr_src[pos] = p.x;
  }
}

// ---------------------------------------------------------------------------
// Gather aggregation over PRE-SCALED fp16 rows Hs[i] = h[i]*dinv[i]:
//   Out[i] = act( dinv[i] * (Hs[i] + sum_j Hs[csr_src[j]]) + bias )
// OUT16: write fp16 (hidden); else fp32 (final output).
// ---------------------------------------------------------------------------
struct F8 {
  float x0, x1, x2, x3, x4, x5, x6, x7;
};

__device__ __forceinline__ void add_h8(F8& a, const __half* p) {
  int4 r = *(const int4*)p;  // 8 halves
  const __half2* h = (const __half2*)&r;
  float2 f0 = __half22float2(h[0]);
  float2 f1 = __half22float2(h[1]);
  float2 f2 = __half22float2(h[2]);
  float2 f3 = __half22float2(h[3]);
  a.x0 += f0.x; a.x1 += f0.y; a.x2 += f1.x; a.x3 += f1.y;
  a.x4 += f2.x; a.x5 += f2.y; a.x6 += f3.x; a.x7 += f3.y;
}

template <int C, bool RELU, bool OUT16>
__global__ __launch_bounds__(256) void gather_kernel(const int* __restrict__ row_start,
                                                     const int* __restrict__ csr_src,
                                                     const float* __restrict__ dinv,
                                                     const __half* __restrict__ Hs,
                                                     const float* __restrict__ bias,
                                                     void* __restrict__ OutPtr) {
  constexpr int TPN = C / 8;  // threads per node (16 or 8)
  int gid = blockIdx.x * 256 + threadIdx.x;
  int i = gid / TPN;
  int c8 = (gid % TPN) * 8;
  if (i >= NNODES) return;

  const float di = dinv[i];
  const int beg = row_start[i];
  const int end = row_start[i + 1];

  F8 a0 = {}, a1 = {}, a2 = {}, a3 = {};
  add_h8(a0, &Hs[(size_t)i * C + c8]);  // self term (pre-scaled)

  int j = beg;
  for (; j + 8 <= end; j += 8) {
    int s0 = csr_src[j + 0], s1 = csr_src[j + 1], s2 = csr_src[j + 2], s3 = csr_src[j + 3];
    int s4 = csr_src[j + 4], s5 = csr_src[j + 5], s6 = csr_src[j + 6], s7 = csr_src[j + 7];
    add_h8(a0, &Hs[(size_t)s0 * C + c8]);
    add_h8(a1, &Hs[(size_t)s1 * C + c8]);
    add_h8(a2, &Hs[(size_t)s2 * C + c8]);
    add_h8(a3, &Hs[(size_t)s3 * C + c8]);
    add_h8(a0, &Hs[(size_t)s4 * C + c8]);
    add_h8(a1, &Hs[(size_t)s5 * C + c8]);
    add_h8(a2, &Hs[(size_t)s6 * C + c8]);
    add_h8(a3, &Hs[(size_t)s7 * C + c8]);
  }
  for (; j + 2 <= end; j += 2) {
    int s0 = csr_src[j + 0], s1 = csr_src[j + 1];
    add_h8(a0, &Hs[(size_t)s0 * C + c8]);
    add_h8(a1, &Hs[(size_t)s1 * C + c8]);
  }
  if (j < end) {
    add_h8(a0, &Hs[(size_t)csr_src[j] * C + c8]);
  }

  float s0 = a0.x0 + a1.x0 + a2.x0 + a3.x0;
  float s1 = a0.x1 + a1.x1 + a2.x1 + a3.x1;
  float s2 = a0.x2 + a1.x2 + a2.x2 + a3.x2;
  float s3 = a0.x3 + a1.x3 + a2.x3 + a3.x3;
  float s4 = a0.x4 + a1.x4 + a2.x4 + a3.x4;
  float s5 = a0.x5 + a1.x5 + a2.x5 + a3.x5;
  float s6 = a0.x6 + a1.x6 + a2.x6 + a3.x6;
  float s7 = a0.x7 + a1.x7 + a2.x7 + a3.x7;

  float4 b0 = *(const float4*)&bias[c8];
  float4 b1 = *(const float4*)&bias[c8 + 4];
  float o0 = fmaf(s0, di, b0.x);
  float o1 = fmaf(s1, di, b0.y);
  float o2 = fmaf(s2, di, b0.z);
  float o3 = fmaf(s3, di, b0.w);
  float o4 = fmaf(s4, di, b1.x);
  float o5 = fmaf(s5, di, b1.y);
  float o6 = fmaf(s6, di, b1.z);
  float o7 = fmaf(s7, di, b1.w);
  if (RELU) {
    o0 = o0 > 0.f ? o0 : 0.f;
    o1 = o1 > 0.f ? o1 : 0.f;
    o2 = o2 > 0.f ? o2 : 0.f;
    o3 = o3 > 0.f ? o3 : 0.f;
    o4 = o4 > 0.f ? o4 : 0.f;
    o5 = o5 > 0.f ? o5 : 0.f;
    o6 = o6 > 0.f ? o6 : 0.f;
    o7 = o7 > 0.f ? o7 : 0.f;
  }
  if (OUT16) {
    half8 hv = {(_Float16)o0, (_Float16)o1, (_Float16)o2, (_Float16)o3,
                (_Float16)o4, (_Float16)o5, (_Float16)o6, (_Float16)o7};
    *(half8*)((_Float16*)OutPtr + (size_t)i * C + c8) = hv;
  } else {
    float* Out = (float*)OutPtr;
    float4 v0 = make_float4(o0, o1, o2, o3);
    float4 v1 = make_float4(o4, o5, o6, o7);
    *(float4*)&Out[(size_t)i * C + c8] = v0;
    *(float4*)&Out[(size_t)i * C + c8 + 4] = v1;
  }
}

// ===========================================================================
// MFMA fp16 GEMM: Hout[M,N] = fp16( (X[M,K] @ W[K,N]) * scale[row] )
// 64-row M-tile per block, 4 waves x 16 rows. W in LDS transposed [n][k],
// A-tile in LDS [m][k], both fp16 with +8-half row pad.
// Fragment layouts (HW-verified m89/m91/m120):
//   A: m=lane&15, k=8*(lane>>4)+j ; B: n=lane&15, same k ;
//   D: row=4*(lane>>4)+reg, col=lane&15.
// ===========================================================================
template <int K, int N, bool A_F16>
__global__ __launch_bounds__(256) void mfma_gemm_kernel(const void* __restrict__ Xv,
                                                        const float* __restrict__ Wm,
                                                        const float* __restrict__ scale,
                                                        _Float16* __restrict__ Hout,
                                                        int M) {
  constexpr int KP = K + 8;  // padded row stride in halves (136)
  __shared__ alignas(16) _Float16 Alds[64 * KP];
  __shared__ alignas(16) _Float16 Wlds[N * KP];

  const int tid = threadIdx.x;
  const int row0 = blockIdx.x * 64;

  // ---- stage W (KxN fp32 row-major) -> Wlds[n][k] fp16, 4x4 transpose ----
  constexpr int TILES = (K / 4) * (N / 4);
  for (int tile = tid; tile < TILES; tile += 256) {
    int kt = tile / (N / 4);
    int nt = tile % (N / 4);
    const float* wp = &Wm[(4 * kt) * N + 4 * nt];
    float4 r0 = *(const float4*)(wp);
    float4 r1 = *(const float4*)(wp + N);
    float4 r2 = *(const float4*)(wp + 2 * N);
    float4 r3 = *(const float4*)(wp + 3 * N);
    half4 c0 = {(_Float16)r0.x, (_Float16)r1.x, (_Float16)r2.x, (_Float16)r3.x};
    half4 c1 = {(_Float16)r0.y, (_Float16)r1.y, (_Float16)r2.y, (_Float16)r3.y};
    half4 c2 = {(_Float16)r0.z, (_Float16)r1.z, (_Float16)r2.z, (_Float16)r3.z};
    half4 c3 = {(_Float16)r0.w, (_Float16)r1.w, (_Float16)r2.w, (_Float16)r3.w};
    *(half4*)&Wlds[(4 * nt + 0) * KP + 4 * kt] = c0;
    *(half4*)&Wlds[(4 * nt + 1) * KP + 4 * kt] = c1;
    *(half4*)&Wlds[(4 * nt + 2) * KP + 4 * kt] = c2;
    *(half4*)&Wlds[(4 * nt + 3) * KP + 4 * kt] = c3;
  }

  // ---- stage A tile (64 x K) -> Alds fp16 ----
  if (A_F16) {
    const _Float16* Xh = (const _Float16*)Xv;
    constexpr int H8PR = K / 8;  // half8 per row (16)
    constexpr int TOT = 64 * H8PR;
    for (int idx = tid; idx < TOT; idx += 256) {
      int lr = idx / H8PR;
      int c8 = (idx % H8PR) * 8;
      int gr = row0 + lr;
      if (gr > M - 1) gr = M - 1;
      int4 v = *(const int4*)&Xh[(size_t)gr * K + c8];
      *(int4*)&Alds[lr * KP + c8] = v;
    }
  } else {
    const float* Xf = (const float*)Xv;
    constexpr int F4PR = K / 4;  // float4 per row (32)
    constexpr int TOT = 64 * F4PR;
    for (int idx = tid; idx < TOT; idx += 256) {
      int lr = idx / F4PR;
      int c4 = (idx % F4PR) * 4;
      int gr = row0 + lr;
      if (gr > M - 1) gr = M - 1;
      float4 v = *(const float4*)&Xf[(size_t)gr * K + c4];
      half4 h = {(_Float16)v.x, (_Float16)v.y, (_Float16)v.z, (_Float16)v.w};
      *(half4*)&Alds[lr * KP + c4] = h;
    }
  }
  __syncthreads();

  // ---- compute ----
  const int w = tid >> 6;
  const int lane = tid & 63;
  const int g = lane >> 4;
  const int mi = lane & 15;
  constexpr int NT = N / 16;

  floatx4 acc[NT];
#pragma unroll
  for (int t = 0; t < NT; ++t) acc[t] = (floatx4){0.f, 0.f, 0.f, 0.f};

  const _Float16* arow = &Alds[(w * 16 + mi) * KP];
#pragma unroll
  for (int ks = 0; ks < K / 32; ++ks) {
    half8 a = *(const half8*)(arow + ks * 32 + g * 8);
#pragma unroll
    for (int t = 0; t < NT; ++t) {
      half8 b = *(const half8*)&Wlds[(t * 16 + mi) * KP + ks * 32 + g * 8];
      acc[t] = __builtin_amdgcn_mfma_f32_16x16x32_f16(a, b, acc[t], 0, 0, 0);
    }
  }

  // ---- epilogue: scale by dinv[row], store fp16 ----
#pragma unroll
  for (int r = 0; r < 4; ++r) {
    int grow = row0 + w * 16 + 4 * g + r;
    if (grow < M) {
      float s = scale[grow];
      _Float16* orow = Hout + (size_t)grow * N + mi;
#pragma unroll
      for (int t = 0; t < NT; ++t) orow[t * 16] = (_Float16)(acc[t][r] * s);
    }
  }
}

// ===========================================================================
// Launch
// ===========================================================================
extern "C" void kernel_launch(void* const* d_in, const int* in_sizes, int n_in,
                              void* d_out, int out_size, void* d_ws, size_t ws_size,
                              hipStream_t stream) {
  const float* x = (const float*)d_in[0];
  const void* eidx = d_in[1];
  const float* W1 = (const float*)d_in[2];
  const float* b1 = (const float*)d_in[3];
  const float* W2 = (const float*)d_in[4];
  const float* b2 = (const float*)d_in[5];
  float* out = (float*)d_out;
  char* ws = (char*)d_ws;

  // Workspace layout (512B-aligned, ~84.4 MB; harness provides >=110 MB):
  float* dinv      = (float*)(ws + 0);           //    400,000 B
  int*   row_start = (int*)(ws + 401408);        //    400,004 B
  int*   cursor    = (int*)(ws + 802816);        //    400,000 B  [histogram in]
  int*   flag      = (int*)(ws + 1203200);       //          4 B
  int*   partial   = (int*)(ws + 1203712);       //      1,564 B
  int*   bcur      = (int*)(ws + 1205760);       //         32 B
  int2*  ebuf      = (int2*)(ws + 1206272);      // 25,600,000 B (8 buckets x 400k int2)
  int*   csr_src   = (int*)(ws + 26806784);      //  6,400,000 B
  _Float16* h1     = (_Float16*)(ws + 33207296); // 25,600,000 B (fp16 Hs; reused layer 2)
  _Float16* hidden = (_Float16*)(ws + 58807808); // 25,600,000 B (fp16)
  _Float16* h2 = h1;

  detect_idx_kernel<<<1, 64, 0, stream>>>(eidx, flag);
  zero_int_kernel<<<(NNODES + 255) / 256, 256, 0, stream>>>(cursor, NNODES);
  init_bcur_kernel<<<1, 64, 0, stream>>>(bcur);
  partition_kernel<<<PART_BLOCKS, 256, 0, stream>>>(eidx, flag, cursor, bcur, ebuf);
  scan_partial_kernel<<<SCAN_BLOCKS, 256, 0, stream>>>(cursor, partial);
  scan_base_kernel<<<1, 512, 0, stream>>>(partial);
  scan_final_kernel<<<SCAN_BLOCKS, 256, 0, stream>>>(cursor, partial, row_start, cursor, dinv);
  fill_bucket_kernel<<<XCD_COUNT * FILL_BPB, 256, 0, stream>>>(ebuf, bcur, cursor, csr_src);

  const int GB = (NNODES + 63) / 64;  // 1563 M-tiles

  // Layer 1: Hs1 = fp16((x @ W1) * dinv); hidden = fp16(relu(di*(Hs1[i]+sum)+b1))
  mfma_gemm_kernel<IN_C, HID_C, false>
      <<<GB, 256, 0, stream>>>(x, W1, dinv, h1, NNODES);
  gather_kernel<HID_C, true, true>
      <<<(NNODES * (HID_C / 8) + 255) / 256, 256, 0, stream>>>(row_start, csr_src, dinv,
                                                               (const __half*)h1, b1, hidden);
  // Layer 2: Hs2 = fp16((hidden @ W2) * dinv); out = di*(Hs2[i]+sum)+b2 (fp32)
  mfma_gemm_kernel<HID_C, OUT_C, true>
      <<<GB, 256, 0, stream>>>(hidden, W2, dinv, h2, NNODES);
  gather_kernel<OUT_C, false, false>
      <<<(NNODES * (OUT_C / 8) + 255) / 256, 256, 0, stream>>>(row_start, csr_src, dinv,
                                                               (const __half*)h2, b2, out);
}

// Round 8
// 319.395 us; speedup vs baseline: 1.1929x; 1.1929x over previous
//
#include <hip/hip_runtime.h>
#include <hip/hip_fp16.h>

// Problem constants (fixed-size problem)
#define NNODES 100000
#define NEDGES 1600000
#define IN_C   128
#define HID_C  128
#define OUT_C  64

#define XCD_COUNT   8
#define XCD_NODES   ((NNODES + XCD_COUNT - 1) / XCD_COUNT)  // 12500
#define FILL_CHUNKS 80
#define EDGES_PER_CHUNK ((NEDGES + FILL_CHUNKS - 1) / FILL_CHUNKS)  // 20000

// Padded adjacency: deg ~ Poisson(16); P(deg>=64) ~ 3e-22/node. Overflow
// list keeps exactness for any input.
#define CAP     64
#define OVF_MAX 4096

typedef __attribute__((ext_vector_type(8))) _Float16 half8;
typedef __attribute__((ext_vector_type(4))) _Float16 half4;
typedef __attribute__((ext_vector_type(4))) float floatx4;

// ---------------------------------------------------------------------------
// Index width handling (int64 per reference vs int32 from JAX default)
// ---------------------------------------------------------------------------
__device__ __forceinline__ long long load_idx(const void* p, long long i, int is64) {
  return is64 ? ((const long long*)p)[i] : (long long)((const int*)p)[i];
}

__global__ void detect_idx_kernel(const void* eidx, int* flag) {
  const unsigned* w = (const unsigned*)eidx;
  int lane = threadIdx.x & 63;
  unsigned v = w[2 * lane + 1];
  unsigned long long bad = __ballot(v != 0u);
  if (lane == 0) *flag = (bad == 0ull) ? 1 : 0;
}

// ===========================================================================
// Adjacency build: ONE atomic pass (fused histogram + placement)
// ===========================================================================

__global__ void zero_cnt_kernel(int* cnt, int* ovf_cnt) {
  int i = blockIdx.x * 256 + threadIdx.x;
  if (i < NNODES) cnt[i] = 0;
  if (i == 0) *ovf_cnt = 0;
}

// Atomic-free compress of edge indices to int32 (streamed once).
__global__ void compress_kernel(const void* eidx, const int* __restrict__ flag,
                                int* __restrict__ src32, int* __restrict__ dst32) {
  int e = blockIdx.x * 256 + threadIdx.x;
  if (e < NEDGES) {
    int is64 = *flag;
    src32[e] = (int)load_idx(eidx, e, is64);
    dst32[e] = (int)load_idx(eidx, (long long)NEDGES + e, is64);
  }
}

// XCD-sliced fused fill: k = atomicAdd(cnt[d]) gives BOTH the in-degree and
// the slot. Block b (xcd = b&7 round-robin heuristic) only takes dst in its
// 12.5K slice -> cnt slice (50 KB) and pad_csr slice (3.2 MB) stay L2-local.
__global__ __launch_bounds__(256) void fill_fused_kernel(const int* __restrict__ src32,
                                                         const int* __restrict__ dst32,
                                                         int* __restrict__ cnt,
                                                         int* __restrict__ pad_csr,
                                                         int* __restrict__ ovf_cnt,
                                                         int2* __restrict__ ovf) {
  const int xcd = blockIdx.x & (XCD_COUNT - 1);
  const int chunk = blockIdx.x >> 3;
  const int lo = xcd * XCD_NODES;
  const int e_beg = chunk * EDGES_PER_CHUNK;
  const int e_end = min(e_beg + EDGES_PER_CHUNK, NEDGES);
  for (int e = e_beg + threadIdx.x; e < e_end; e += 256) {
    int d = dst32[e];
    if ((unsigned)(d - lo) < (unsigned)XCD_NODES) {
      int s = src32[e];
      int k = atomicAdd(&cnt[d], 1);
      if (k < CAP) {
        pad_csr[d * CAP + k] = s;
      } else {
        int p = atomicAdd(ovf_cnt, 1);
        if (p < OVF_MAX) ovf[p] = make_int2(s, d);
      }
    }
  }
}

__global__ void rsqrt_deg_kernel(const int* __restrict__ cnt, float* __restrict__ dinv) {
  int i = blockIdx.x * 256 + threadIdx.x;
  if (i < NNODES) dinv[i] = rsqrtf((float)(cnt[i] + 1));
}

// ---------------------------------------------------------------------------
// Gather aggregation over PRE-SCALED fp16 rows Hs[i] = h[i]*dinv[i]:
//   Out[i] = act( dinv[i] * (Hs[i] + sum_j Hs[adj(i,j)]) + bias )
// Edge lists from padded adjacency pad_csr[i*CAP .. i*CAP+min(cnt,CAP)).
// OUT16: write fp16 (hidden); else fp32 (final output).
// ---------------------------------------------------------------------------
struct F8 {
  float x0, x1, x2, x3, x4, x5, x6, x7;
};

__device__ __forceinline__ void add_h8(F8& a, const __half* p) {
  int4 r = *(const int4*)p;  // 8 halves
  const __half2* h = (const __half2*)&r;
  float2 f0 = __half22float2(h[0]);
  float2 f1 = __half22float2(h[1]);
  float2 f2 = __half22float2(h[2]);
  float2 f3 = __half22float2(h[3]);
  a.x0 += f0.x; a.x1 += f0.y; a.x2 += f1.x; a.x3 += f1.y;
  a.x4 += f2.x; a.x5 += f2.y; a.x6 += f3.x; a.x7 += f3.y;
}

template <int C, bool RELU, bool OUT16>
__global__ __launch_bounds__(256) void gather_kernel(const int* __restrict__ cnt,
                                                     const int* __restrict__ pad_csr,
                                                     const float* __restrict__ dinv,
                                                     const __half* __restrict__ Hs,
                                                     const float* __restrict__ bias,
                                                     const int* __restrict__ ovf_cnt,
                                                     const int2* __restrict__ ovf,
                                                     void* __restrict__ OutPtr) {
  constexpr int TPN = C / 8;  // threads per node (16 or 8)
  int gid = blockIdx.x * 256 + threadIdx.x;
  int i = gid / TPN;
  int c8 = (gid % TPN) * 8;
  if (i >= NNODES) return;

  const float di = dinv[i];
  const int deg = cnt[i];
  const int beg = i * CAP;
  const int end = beg + min(deg, CAP);
  const int* __restrict__ lst = pad_csr;

  F8 a0 = {}, a1 = {}, a2 = {}, a3 = {};
  add_h8(a0, &Hs[(size_t)i * C + c8]);  // self term (pre-scaled)

  int j = beg;
  for (; j + 8 <= end; j += 8) {
    int s0 = lst[j + 0], s1 = lst[j + 1], s2 = lst[j + 2], s3 = lst[j + 3];
    int s4 = lst[j + 4], s5 = lst[j + 5], s6 = lst[j + 6], s7 = lst[j + 7];
    add_h8(a0, &Hs[(size_t)s0 * C + c8]);
    add_h8(a1, &Hs[(size_t)s1 * C + c8]);
    add_h8(a2, &Hs[(size_t)s2 * C + c8]);
    add_h8(a3, &Hs[(size_t)s3 * C + c8]);
    add_h8(a0, &Hs[(size_t)s4 * C + c8]);
    add_h8(a1, &Hs[(size_t)s5 * C + c8]);
    add_h8(a2, &Hs[(size_t)s6 * C + c8]);
    add_h8(a3, &Hs[(size_t)s7 * C + c8]);
  }
  for (; j + 2 <= end; j += 2) {
    int s0 = lst[j + 0], s1 = lst[j + 1];
    add_h8(a0, &Hs[(size_t)s0 * C + c8]);
    add_h8(a1, &Hs[(size_t)s1 * C + c8]);
  }
  if (j < end) {
    add_h8(a0, &Hs[(size_t)lst[j] * C + c8]);
  }

  if (deg > CAP) {  // exactness guard; never taken for Poisson(16) degrees
    int n = min(*ovf_cnt, OVF_MAX);
    for (int t = 0; t < n; ++t) {
      int2 p = ovf[t];
      if (p.y == i) add_h8(a0, &Hs[(size_t)p.x * C + c8]);
    }
  }

  float s0 = a0.x0 + a1.x0 + a2.x0 + a3.x0;
  float s1 = a0.x1 + a1.x1 + a2.x1 + a3.x1;
  float s2 = a0.x2 + a1.x2 + a2.x2 + a3.x2;
  float s3 = a0.x3 + a1.x3 + a2.x3 + a3.x3;
  float s4 = a0.x4 + a1.x4 + a2.x4 + a3.x4;
  float s5 = a0.x5 + a1.x5 + a2.x5 + a3.x5;
  float s6 = a0.x6 + a1.x6 + a2.x6 + a3.x6;
  float s7 = a0.x7 + a1.x7 + a2.x7 + a3.x7;

  float4 b0 = *(const float4*)&bias[c8];
  float4 b1 = *(const float4*)&bias[c8 + 4];
  float o0 = fmaf(s0, di, b0.x);
  float o1 = fmaf(s1, di, b0.y);
  float o2 = fmaf(s2, di, b0.z);
  float o3 = fmaf(s3, di, b0.w);
  float o4 = fmaf(s4, di, b1.x);
  float o5 = fmaf(s5, di, b1.y);
  float o6 = fmaf(s6, di, b1.z);
  float o7 = fmaf(s7, di, b1.w);
  if (RELU) {
    o0 = o0 > 0.f ? o0 : 0.f;
    o1 = o1 > 0.f ? o1 : 0.f;
    o2 = o2 > 0.f ? o2 : 0.f;
    o3 = o3 > 0.f ? o3 : 0.f;
    o4 = o4 > 0.f ? o4 : 0.f;
    o5 = o5 > 0.f ? o5 : 0.f;
    o6 = o6 > 0.f ? o6 : 0.f;
    o7 = o7 > 0.f ? o7 : 0.f;
  }
  if (OUT16) {
    half8 hv = {(_Float16)o0, (_Float16)o1, (_Float16)o2, (_Float16)o3,
                (_Float16)o4, (_Float16)o5, (_Float16)o6, (_Float16)o7};
    *(half8*)((_Float16*)OutPtr + (size_t)i * C + c8) = hv;
  } else {
    float* Out = (float*)OutPtr;
    float4 v0 = make_float4(o0, o1, o2, o3);
    float4 v1 = make_float4(o4, o5, o6, o7);
    *(float4*)&Out[(size_t)i * C + c8] = v0;
    *(float4*)&Out[(size_t)i * C + c8 + 4] = v1;
  }
}

// ===========================================================================
// MFMA fp16 GEMM: Hout[M,N] = fp16( (X[M,K] @ W[K,N]) * scale[row] )
// 64-row M-tile per block, 4 waves x 16 rows. W in LDS transposed [n][k],
// A-tile in LDS [m][k], both fp16 with +8-half row pad.
// Fragment layouts (HW-verified m89/m91/m120):
//   A: m=lane&15, k=8*(lane>>4)+j ; B: n=lane&15, same k ;
//   D: row=4*(lane>>4)+reg, col=lane&15.
// ===========================================================================
template <int K, int N, bool A_F16>
__global__ __launch_bounds__(256) void mfma_gemm_kernel(const void* __restrict__ Xv,
                                                        const float* __restrict__ Wm,
                                                        const float* __restrict__ scale,
                                                        _Float16* __restrict__ Hout,
                                                        int M) {
  constexpr int KP = K + 8;  // padded row stride in halves (136)
  __shared__ alignas(16) _Float16 Alds[64 * KP];
  __shared__ alignas(16) _Float16 Wlds[N * KP];

  const int tid = threadIdx.x;
  const int row0 = blockIdx.x * 64;

  // ---- stage W (KxN fp32 row-major) -> Wlds[n][k] fp16, 4x4 transpose ----
  constexpr int TILES = (K / 4) * (N / 4);
  for (int tile = tid; tile < TILES; tile += 256) {
    int kt = tile / (N / 4);
    int nt = tile % (N / 4);
    const float* wp = &Wm[(4 * kt) * N + 4 * nt];
    float4 r0 = *(const float4*)(wp);
    float4 r1 = *(const float4*)(wp + N);
    float4 r2 = *(const float4*)(wp + 2 * N);
    float4 r3 = *(const float4*)(wp + 3 * N);
    half4 c0 = {(_Float16)r0.x, (_Float16)r1.x, (_Float16)r2.x, (_Float16)r3.x};
    half4 c1 = {(_Float16)r0.y, (_Float16)r1.y, (_Float16)r2.y, (_Float16)r3.y};
    half4 c2 = {(_Float16)r0.z, (_Float16)r1.z, (_Float16)r2.z, (_Float16)r3.z};
    half4 c3 = {(_Float16)r0.w, (_Float16)r1.w, (_Float16)r2.w, (_Float16)r3.w};
    *(half4*)&Wlds[(4 * nt + 0) * KP + 4 * kt] = c0;
    *(half4*)&Wlds[(4 * nt + 1) * KP + 4 * kt] = c1;
    *(half4*)&Wlds[(4 * nt + 2) * KP + 4 * kt] = c2;
    *(half4*)&Wlds[(4 * nt + 3) * KP + 4 * kt] = c3;
  }

  // ---- stage A tile (64 x K) -> Alds fp16 ----
  if (A_F16) {
    const _Float16* Xh = (const _Float16*)Xv;
    constexpr int H8PR = K / 8;  // half8 per row (16)
    constexpr int TOT = 64 * H8PR;
    for (int idx = tid; idx < TOT; idx += 256) {
      int lr = idx / H8PR;
      int c8 = (idx % H8PR) * 8;
      int gr = row0 + lr;
      if (gr > M - 1) gr = M - 1;
      int4 v = *(const int4*)&Xh[(size_t)gr * K + c8];
      *(int4*)&Alds[lr * KP + c8] = v;
    }
  } else {
    const float* Xf = (const float*)Xv;
    constexpr int F4PR = K / 4;  // float4 per row (32)
    constexpr int TOT = 64 * F4PR;
    for (int idx = tid; idx < TOT; idx += 256) {
      int lr = idx / F4PR;
      int c4 = (idx % F4PR) * 4;
      int gr = row0 + lr;
      if (gr > M - 1) gr = M - 1;
      float4 v = *(const float4*)&Xf[(size_t)gr * K + c4];
      half4 h = {(_Float16)v.x, (_Float16)v.y, (_Float16)v.z, (_Float16)v.w};
      *(half4*)&Alds[lr * KP + c4] = h;
    }
  }
  __syncthreads();

  // ---- compute ----
  const int w = tid >> 6;
  const int lane = tid & 63;
  const int g = lane >> 4;
  const int mi = lane & 15;
  constexpr int NT = N / 16;

  floatx4 acc[NT];
#pragma unroll
  for (int t = 0; t < NT; ++t) acc[t] = (floatx4){0.f, 0.f, 0.f, 0.f};

  const _Float16* arow = &Alds[(w * 16 + mi) * KP];
#pragma unroll
  for (int ks = 0; ks < K / 32; ++ks) {
    half8 a = *(const half8*)(arow + ks * 32 + g * 8);
#pragma unroll
    for (int t = 0; t < NT; ++t) {
      half8 b = *(const half8*)&Wlds[(t * 16 + mi) * KP + ks * 32 + g * 8];
      acc[t] = __builtin_amdgcn_mfma_f32_16x16x32_f16(a, b, acc[t], 0, 0, 0);
    }
  }

  // ---- epilogue: scale by dinv[row], store fp16 ----
#pragma unroll
  for (int r = 0; r < 4; ++r) {
    int grow = row0 + w * 16 + 4 * g + r;
    if (grow < M) {
      float s = scale[grow];
      _Float16* orow = Hout + (size_t)grow * N + mi;
#pragma unroll
      for (int t = 0; t < NT; ++t) orow[t * 16] = (_Float16)(acc[t][r] * s);
    }
  }
}

// ===========================================================================
// Launch
// ===========================================================================
extern "C" void kernel_launch(void* const* d_in, const int* in_sizes, int n_in,
                              void* d_out, int out_size, void* d_ws, size_t ws_size,
                              hipStream_t stream) {
  const float* x = (const float*)d_in[0];
  const void* eidx = d_in[1];
  const float* W1 = (const float*)d_in[2];
  const float* b1 = (const float*)d_in[3];
  const float* W2 = (const float*)d_in[4];
  const float* b2 = (const float*)d_in[5];
  float* out = (float*)d_out;
  char* ws = (char*)d_ws;

  // Workspace layout (512B-aligned, ~96.9 MB; harness provides >=110 MB
  // as proven by rounds 2-7):
  int*   flag    = (int*)(ws + 0);            //          4 B
  int*   ovf_cnt = (int*)(ws + 512);          //          4 B
  int*   cnt     = (int*)(ws + 1024);         //    400,000 B
  float* dinv    = (float*)(ws + 401408);     //    400,000 B
  int2*  ovf     = (int2*)(ws + 801792);      //     32,768 B
  int*   src32   = (int*)(ws + 835072);       //  6,400,000 B
  int*   dst32   = (int*)(ws + 7235584);      //  6,400,000 B
  int*   pad_csr = (int*)(ws + 13636096);     // 25,600,000 B (100k x 64 slots)
  _Float16* h1   = (_Float16*)(ws + 39236608);// 25,600,000 B (fp16 Hs; reused layer 2)
  _Float16* hidden = (_Float16*)(ws + 64837120); // 25,600,000 B (fp16)
  _Float16* h2 = h1;

  detect_idx_kernel<<<1, 64, 0, stream>>>(eidx, flag);
  zero_cnt_kernel<<<(NNODES + 255) / 256, 256, 0, stream>>>(cnt, ovf_cnt);
  compress_kernel<<<(NEDGES + 255) / 256, 256, 0, stream>>>(eidx, flag, src32, dst32);
  fill_fused_kernel<<<XCD_COUNT * FILL_CHUNKS, 256, 0, stream>>>(src32, dst32, cnt,
                                                                 pad_csr, ovf_cnt, ovf);
  rsqrt_deg_kernel<<<(NNODES + 255) / 256, 256, 0, stream>>>(cnt, dinv);

  const int GB = (NNODES + 63) / 64;  // 1563 M-tiles

  // Layer 1: Hs1 = fp16((x @ W1) * dinv); hidden = fp16(relu(di*(Hs1[i]+sum)+b1))
  mfma_gemm_kernel<IN_C, HID_C, false>
      <<<GB, 256, 0, stream>>>(x, W1, dinv, h1, NNODES);
  gather_kernel<HID_C, true, true>
      <<<(NNODES * (HID_C / 8) + 255) / 256, 256, 0, stream>>>(cnt, pad_csr, dinv,
                                                               (const __half*)h1, b1,
                                                               ovf_cnt, ovf, hidden);
  // Layer 2: Hs2 = fp16((hidden @ W2) * dinv); out = di*(Hs2[i]+sum)+b2 (fp32)
  mfma_gemm_kernel<HID_C, OUT_C, true>
      <<<GB, 256, 0, stream>>>(hidden, W2, dinv, h2, NNODES);
  gather_kernel<OUT_C, false, false>
      <<<(NNODES * (OUT_C / 8) + 255) / 256, 256, 0, stream>>>(cnt, pad_csr, dinv,
                                                               (const __half*)h2, b2,
                                                               ovf_cnt, ovf, out);
}